// Round 18
// baseline (184.276 us; speedup 1.0000x reference)
//
#include <hip/hip_runtime.h>

#define N_NODES 4096
#define F_IN 512
#define H_DIM 128
#define C_DIM 16
#define EPSF 1e-8f
#define LOG2E 1.4426950408889634f
#define SMAX 2.0f   // static softmax max: logits = cos/tau*log2e + log2(adj+eps) < 2 always
#define NKS0 4      // layer-0 K-splits (halved: fewer DRAM row-streams)
#define KLEN0 (N_NODES / NKS0)
#define NT0 (KLEN0 / 32)
#define NGRP0 (NT0 / 2)
#define NKS1 8      // layer-1 K-splits

typedef __attribute__((ext_vector_type(8))) short bf16x8;
typedef __attribute__((ext_vector_type(4))) short bf16x4;
typedef __attribute__((ext_vector_type(4))) float f32x4;

__device__ __forceinline__ ushort f2bf(float f){
  union { float f; unsigned u; } v; v.f = f;
  unsigned u = v.u;
  return (ushort)((u + 0x7fffu + ((u >> 16) & 1u)) >> 16);
}
__device__ __forceinline__ float bf2f(ushort h){
  union { unsigned u; float f; } v; v.u = ((unsigned)h) << 16;
  return v.f;
}

// ---------------------------------------------------------------------------
// K1: h = x @ W0 for 3 branches, k-split x2 within block (256 thr, 4 waves);
//     row norms; write hn (bf16, row-major) and hvT (bf16 [3][128][4096]).
// ---------------------------------------------------------------------------
__global__ __launch_bounds__(256) void proj0_kernel(
    const float* __restrict__ x,
    const float* __restrict__ Wl, const float* __restrict__ Wh,
    const float* __restrict__ Wm,
    ushort* __restrict__ hn, ushort* __restrict__ hvT)
{
  const int t = threadIdx.x;
  const int d = t & 127;
  const int half = t >> 7;
  const int r0 = blockIdx.x * 8;
  __shared__ float xs[8][F_IN];
  for (int i = t; i < 8 * F_IN; i += 256)
    xs[i >> 9][i & 511] = x[(size_t)(r0 + (i >> 9)) * F_IN + (i & 511)];
  __syncthreads();

  float acc0[8], acc1[8], acc2[8];
#pragma unroll
  for (int r = 0; r < 8; r++) { acc0[r] = 0.f; acc1[r] = 0.f; acc2[r] = 0.f; }

  const int k0 = half * (F_IN / 2);
  for (int k = k0; k < k0 + F_IN / 2; k++) {
    float wl = Wl[k * H_DIM + d];
    float wh = Wh[k * H_DIM + d];
    float wm = Wm[k * H_DIM + d];
#pragma unroll
    for (int r = 0; r < 8; r++) {
      float xv = xs[r][k];
      acc0[r] = fmaf(xv, wl, acc0[r]);
      acc1[r] = fmaf(xv, wh, acc1[r]);
      acc2[r] = fmaf(xv, wm, acc2[r]);
    }
  }

  // cross-half combine
  __shared__ float part[3][8][128];
  if (half == 1) {
#pragma unroll
    for (int r = 0; r < 8; r++) {
      part[0][r][d] = acc0[r]; part[1][r][d] = acc1[r]; part[2][r][d] = acc2[r];
    }
  }
  __syncthreads();
  if (half == 0) {
#pragma unroll
    for (int r = 0; r < 8; r++) {
      acc0[r] += part[0][r][d]; acc1[r] += part[1][r][d]; acc2[r] += part[2][r][d];
    }
  }

  __shared__ float red[24][2];
  const int wv = t >> 6;        // 0..1 for half==0
  const int lane = t & 63;

#define REDUCE_BRANCH(ACC, B)                                        \
  _Pragma("unroll")                                                  \
  for (int r = 0; r < 8; r++) {                                      \
    float v = ACC[r] * ACC[r];                                       \
    v += __shfl_down(v, 32); v += __shfl_down(v, 16);                \
    v += __shfl_down(v, 8);  v += __shfl_down(v, 4);                 \
    v += __shfl_down(v, 2);  v += __shfl_down(v, 1);                 \
    if (lane == 0) red[(B) * 8 + r][wv] = v;                         \
  }
  if (half == 0) {
    REDUCE_BRANCH(acc0, 0)
    REDUCE_BRANCH(acc1, 1)
    REDUCE_BRANCH(acc2, 2)
  }
  __syncthreads();

#define WRITE_BRANCH(ACC, B)                                                   \
  _Pragma("unroll")                                                            \
  for (int r = 0; r < 8; r++) {                                                \
    float nrm = sqrtf(red[(B) * 8 + r][0] + red[(B) * 8 + r][1]);              \
    float rn = 1.0f / fmaxf(nrm, EPSF);                                        \
    float h = ACC[r];                                                          \
    hn[((size_t)(B) * N_NODES + r0 + r) * H_DIM + d] = f2bf(h * rn);           \
    hvT[((size_t)(B) * H_DIM + d) * N_NODES + r0 + r] = f2bf(h);               \
  }
  if (half == 0) {
    WRITE_BRANCH(acc0, 0)
    WRITE_BRANCH(acc1, 1)
    WRITE_BRANCH(acc2, 2)
  }
#undef REDUCE_BRANCH
#undef WRITE_BRANCH
}

// ---------------------------------------------------------------------------
// K2: flash attention layer 0 — R13-verified dataflow (swapped QK^T,
//     in-register P). adj staged in 2-TILE GROUPS (64 cols): each
//     global_load_lds covers 4 rows x 256B contiguous (2x DRAM burst),
//     staged every other tile. NKS0=4 halves concurrent row-streams.
//     Counted vmcnt(8)/4/0, raw barrier pairs. 4 waves, 64 q-rows/block.
// ---------------------------------------------------------------------------
__global__ __launch_bounds__(256) void flash0_kernel(
    const ushort* __restrict__ hn, const ushort* __restrict__ hvT,
    const float* __restrict__ adj_l, const float* __restrict__ adj_h,
    const float* __restrict__ adj_m,
    float* __restrict__ pl0, ushort* __restrict__ pO)
{
  const int tid = threadIdx.x;
  const int w = tid >> 6;
  const int lane = tid & 63;
  const int lr = lane & 15;
  const int lg = lane >> 4;
  const int ks = blockIdx.y;
  const int b = blockIdx.z;
  const int qblk = blockIdx.x * 64;
  const int q0 = qblk + w * 16;
  const float* adj = (b == 0) ? adj_l : (b == 1) ? adj_h : adj_m;
  const ushort* Qg = hn + (size_t)b * N_NODES * H_DIM;
  const ushort* VTg = hvT + (size_t)b * H_DIM * N_NODES;
  const int kbase = ks * KLEN0;

  __shared__ ushort sK[2][32 * 128];   // per-tile, chunk-swizzled (8KB each)
  __shared__ ushort sV[2][128 * 32];   // per-tile, chunk-swizzled (8KB each)
  __shared__ float  sAdj[2][64 * 64];  // per-GROUP (2 tiles, 64 cols), 16KB each

  // Q B-fragments (one-time global read)
  bf16x8 qf[4];
  {
    const ushort* qp = Qg + (size_t)(q0 + lr) * H_DIM + lg * 8;
#pragma unroll
    for (int u = 0; u < 4; u++) qf[u] = *(const bf16x8*)(qp + 32 * u);
  }

  f32x4 o[8];
#pragma unroll
  for (int dt = 0; dt < 8; dt++) o[dt] = (f32x4){0.f, 0.f, 0.f, 0.f};
  float lsum = 0.f;

  // --- K/V staging slots (R8-verified) ---
  const int sA = w * 128 + lane;
  const int sB = sA + 64;
  const int kkA = sA >> 4, kcA = sA & 15;
  const int kkB = sB >> 4, kcB = sB & 15;
  const size_t kOffA = (size_t)kkA * H_DIM + ((size_t)(kcA ^ (kkA & 7)) << 3);
  const size_t kOffB = (size_t)kkB * H_DIM + ((size_t)(kcB ^ (kkB & 7)) << 3);
  const int dA = sA >> 2, vcA = sA & 3;
  const int dB = sB >> 2, vcB = sB & 3;
  const size_t vOffA = (size_t)dA * N_NODES + ((size_t)(vcA ^ ((dA >> 1) & 3)) << 3);
  const size_t vOffB = (size_t)dB * N_NODES + ((size_t)(vcB ^ ((dB >> 1) & 3)) << 3);
  // --- adj group staging: 1024 units of 16B; op j of wave w covers units
  //     [w*64 + j*256, +64): 4 rows x 256B contiguous per op.
  //     unit u: row r=u>>4, stored chunk c=u&15 holds logical chunk c^(r&7).
  size_t aOffJ[4];
#pragma unroll
  for (int j = 0; j < 4; j++) {
    const int u = w * 64 + lane + j * 256;
    const int r = u >> 4, c = u & 15;
    aOffJ[j] = (size_t)r * N_NODES + ((size_t)(c ^ (r & 7)) << 2);
  }
  const float* adjq = adj + (size_t)qblk * N_NODES;

#define STAGE_KV(BUF, K0)                                                      \
  {                                                                            \
    const ushort* ksrc = Qg + (size_t)(K0) * H_DIM;                            \
    const ushort* vsrc = VTg + (K0);                                           \
    __builtin_amdgcn_global_load_lds(ksrc + kOffA,                             \
        (char*)&sK[BUF][0] + w * 2048, 16, 0, 0);                              \
    __builtin_amdgcn_global_load_lds(ksrc + kOffB,                             \
        (char*)&sK[BUF][0] + w * 2048 + 1024, 16, 0, 0);                       \
    __builtin_amdgcn_global_load_lds(vsrc + vOffA,                             \
        (char*)&sV[BUF][0] + w * 2048, 16, 0, 0);                              \
    __builtin_amdgcn_global_load_lds(vsrc + vOffB,                             \
        (char*)&sV[BUF][0] + w * 2048 + 1024, 16, 0, 0);                       \
  }
#define STAGE_ADJ(BUF, K0)                                                     \
  {                                                                            \
    const float* asrc = adjq + (K0);                                           \
    __builtin_amdgcn_global_load_lds(asrc + aOffJ[0],                          \
        (char*)&sAdj[BUF][0] + (w * 64 + 0) * 16, 16, 0, 0);                   \
    __builtin_amdgcn_global_load_lds(asrc + aOffJ[1],                          \
        (char*)&sAdj[BUF][0] + (w * 64 + 256) * 16, 16, 0, 0);                 \
    __builtin_amdgcn_global_load_lds(asrc + aOffJ[2],                          \
        (char*)&sAdj[BUF][0] + (w * 64 + 512) * 16, 16, 0, 0);                 \
    __builtin_amdgcn_global_load_lds(asrc + aOffJ[3],                          \
        (char*)&sAdj[BUF][0] + (w * 64 + 768) * 16, 16, 0, 0);                 \
  }

  // Prologue: group 0 adj + tile 0 KV
  STAGE_ADJ(0, kbase)
  STAGE_KV(0, kbase)

  // adj read offsets: lane reads row rL, logical chunk (t&1)*8 + lg (a0) and
  // (t&1)*8 + 4 + lg (a1); stored chunk = lc ^ (rL&7); row stride 256B.
  const int rL = w * 16 + lr;

  for (int t = 0; t < NT0; t++) {
    const int cur = t & 1;            // KV buffer
    const int gb = (t >> 1) & 1;      // adj group buffer
    // barrier A: all waves done with tile t-1 (frees KV buf cur^1; at even t
    // also frees adj buf gb^1, last read at t-1 = end of group (t/2)-1)
    __builtin_amdgcn_s_barrier();
    __builtin_amdgcn_sched_barrier(0);
    if (t + 1 < NT0) STAGE_KV(cur ^ 1, kbase + (t + 1) * 32)
    if ((t & 1) == 0 && (t >> 1) + 1 < NGRP0)
      STAGE_ADJ(gb ^ 1, kbase + ((t >> 1) + 1) * 64)
    // counted wait: everything needed for tile t landed; newer prefetches
    // (kv(t+1): 4 ops, adj(g+1): 4 ops) stay in flight.
    const int rem = NT0 - 1 - t;
    if (rem >= 2)      { asm volatile("s_waitcnt vmcnt(8)" ::: "memory"); }
    else if (rem == 1) { asm volatile("s_waitcnt vmcnt(4)" ::: "memory"); }
    else               { asm volatile("s_waitcnt vmcnt(0)" ::: "memory"); }
    __builtin_amdgcn_sched_barrier(0);
    // barrier B: ALL waves' slices landed
    __builtin_amdgcn_s_barrier();
    __builtin_amdgcn_sched_barrier(0);

    __builtin_amdgcn_s_setprio(1);
    // --- swapped QK^T from LDS: s = mfma(K, Q) -> lane holds S^T ---
    f32x4 s0 = (f32x4){0.f, 0.f, 0.f, 0.f};
    f32x4 s1 = (f32x4){0.f, 0.f, 0.f, 0.f};
    const char* sKc = (const char*)&sK[cur][0];
#pragma unroll
    for (int u = 0; u < 4; u++) {
      const int c0 = lg + 4 * u;
      bf16x8 kf0 = *(const bf16x8*)(sKc + lr * 256 + ((c0 ^ (lr & 7)) << 4));
      bf16x8 kf1 = *(const bf16x8*)(sKc + (lr + 16) * 256 + ((c0 ^ (lr & 7)) << 4));
      s0 = __builtin_amdgcn_mfma_f32_16x16x32_bf16(kf0, qf[u], s0, 0, 0, 0);
      s1 = __builtin_amdgcn_mfma_f32_16x16x32_bf16(kf1, qf[u], s1, 0, 0, 0);
    }
    // adj from LDS group buffer (2-way banks via XOR swizzle)
    const int lc0 = (t & 1) * 8 + lg;
    const int lc1 = lc0 + 4;
    f32x4 a0 = *(const f32x4*)((const char*)&sAdj[gb][0] +
                   rL * 256 + ((lc0 ^ (rL & 7)) << 4));
    f32x4 a1 = *(const f32x4*)((const char*)&sAdj[gb][0] +
                   rL * 256 + ((lc1 ^ (rL & 7)) << 4));
    // --- softmax numerator in registers: P stays as PV A-fragments ---
    bf16x4 pf0, pf1;
#pragma unroll
    for (int r = 0; r < 4; r++) {
      float p0 = exp2f(fmaf(s0[r], LOG2E, -SMAX)) * (a0[r] + EPSF);
      float p1 = exp2f(fmaf(s1[r], LOG2E, -SMAX)) * (a1[r] + EPSF);
      lsum += p0 + p1;
      pf0[r] = (short)f2bf(p0);
      pf1[r] = (short)f2bf(p1);
    }
    // --- PV from LDS: o[dt] accumulates P[16q][32k] @ V[32k][16d] ---
    const char* sVc = (const char*)&sV[cur][0];
#pragma unroll
    for (int dt = 0; dt < 8; dt++) {
      const int dd = dt * 16 + lr;
      const int sw = (dd >> 1) & 3;
      bf16x4 vf0 = *(const bf16x4*)(sVc + dd * 64 +
                     ((((lg >> 1) + 0) ^ sw) << 4) + (lg & 1) * 8);
      bf16x4 vf1 = *(const bf16x4*)(sVc + dd * 64 +
                     ((((lg >> 1) + 2) ^ sw) << 4) + (lg & 1) * 8);
      o[dt] = __builtin_amdgcn_mfma_f32_16x16x16bf16_1k(pf0, vf0, o[dt], 0, 0, 0);
      o[dt] = __builtin_amdgcn_mfma_f32_16x16x16bf16_1k(pf1, vf1, o[dt], 0, 0, 0);
    }
    __builtin_amdgcn_s_setprio(0);
  }
#undef STAGE_KV
#undef STAGE_ADJ

  const int ps = b * NKS0 + ks;
  // denominator: lane (lr,lg) holds partial for q0+lr over its k-slice
  float psum = lsum;
  psum += __shfl_xor(psum, 16);
  psum += __shfl_xor(psum, 32);
  if (lg == 0) pl0[(size_t)ps * N_NODES + q0 + lr] = psum;
  // numerators: o[dt] C/D: row = q0+lg*4+r, col = dt*16+lr (R4-verified)
#pragma unroll
  for (int dt = 0; dt < 8; dt++) {
#pragma unroll
    for (int r = 0; r < 4; r++) {
      pO[((size_t)ps * N_NODES + q0 + lg * 4 + r) * H_DIM + dt * 16 + lr] =
          f2bf(o[dt][r]);
    }
  }
}

// ---------------------------------------------------------------------------
// K3: fused combine0+mix1: merge K-split partials, branch mix + relu, @W1,
//     row norms -> hn1b (bf16 [3][4096][16]); hbT (bf16 [3][16][4096]).
// ---------------------------------------------------------------------------
__global__ __launch_bounds__(128) void mix1_kernel(
    const float* __restrict__ pl0, const ushort* __restrict__ pO,
    const float* __restrict__ bl0, const float* __restrict__ bh0,
    const float* __restrict__ bm0,
    const float* __restrict__ Wl1, const float* __restrict__ Wh1,
    const float* __restrict__ Wm1,
    const float* __restrict__ g0,
    ushort* __restrict__ hn1b, ushort* __restrict__ hbT)
{
  const int q = blockIdx.x;
  const int t = threadIdx.x;
  float ga = g0[0], gb = g0[1], gc = g0[2];
  float gm = fmaxf(ga, fmaxf(gb, gc));
  float e0 = expf(ga - gm), e1 = expf(gb - gm), e2 = expf(gc - gm);
  float ei = 1.0f / (e0 + e1 + e2);

  __shared__ float Ls[3];
  if (t < 3) {
    float L = 0.f;
#pragma unroll
    for (int ks = 0; ks < NKS0; ks++) L += pl0[(size_t)(t * NKS0 + ks) * N_NODES + q];
    Ls[t] = L;
  }
  float O0 = 0.f, O1 = 0.f, O2 = 0.f;
#pragma unroll
  for (int ks = 0; ks < NKS0; ks++) {
    O0 += bf2f(pO[((size_t)(0 * NKS0 + ks) * N_NODES + q) * H_DIM + t]);
    O1 += bf2f(pO[((size_t)(1 * NKS0 + ks) * N_NODES + q) * H_DIM + t]);
    O2 += bf2f(pO[((size_t)(2 * NKS0 + ks) * N_NODES + q) * H_DIM + t]);
  }
  __syncthreads();

  __shared__ float hc[H_DIM];
  hc[t] = e0 * ei * fmaxf(O0 / Ls[0] + bl0[t], 0.f)
        + e1 * ei * fmaxf(O1 / Ls[1] + bh0[t], 0.f)
        + e2 * ei * fmaxf(O2 / Ls[2] + bm0[t], 0.f);
  __syncthreads();

  __shared__ float shb[48];
  if (t < 48) {
    const int b = t >> 4, j = t & 15;
    const float* W = (b == 0) ? Wl1 : (b == 1) ? Wh1 : Wm1;
    float s = 0.f;
    for (int k = 0; k < H_DIM; k++) s = fmaf(hc[k], W[k * C_DIM + j], s);
    shb[t] = s;
  }
  __syncthreads();
  __shared__ float rns[3];
  if (t < 3) {
    float s = 0.f;
#pragma unroll
    for (int j = 0; j < C_DIM; j++) { float u = shb[t * C_DIM + j]; s = fmaf(u, u, s); }
    rns[t] = 1.0f / fmaxf(sqrtf(s), EPSF);
  }
  __syncthreads();
  if (t < 48) {
    const int b = t >> 4, j = t & 15;
    hbT[((size_t)b * C_DIM + j) * N_NODES + q] = f2bf(shb[t]);
    hn1b[((size_t)b * N_NODES + q) * C_DIM + j] = f2bf(shb[t] * rns[b]);
  }
}

// ---------------------------------------------------------------------------
// K4: flash attention layer 1, D=16, MFMA 16x16x16, swapped QK^T, K-split 8.
//     adj staged in LDS [64 q-rows][32 k] double-buffered via global_load_lds
//     (XOR-chunk swizzle both sides); Q/K/V direct (L2-resident).
// ---------------------------------------------------------------------------
__global__ __launch_bounds__(256) void flash1_kernel(
    const ushort* __restrict__ hn1b, const ushort* __restrict__ hbT,
    const float* __restrict__ adj_l, const float* __restrict__ adj_h,
    const float* __restrict__ adj_m,
    float* __restrict__ pl, float* __restrict__ pacc)
{
  const int tid = threadIdx.x;
  const int wid = tid >> 6;
  const int lane = tid & 63;
  const int lr = lane & 15;
  const int lg = lane >> 4;
  const int qblk = blockIdx.x * 64;
  const int q0 = qblk + wid * 16;
  const int ks = blockIdx.y;
  const int b = blockIdx.z;
  const float* adj = (b == 0) ? adj_l : (b == 1) ? adj_h : adj_m;
  const ushort* Qn = hn1b + (size_t)b * N_NODES * C_DIM;
  const ushort* VT = hbT + (size_t)b * C_DIM * N_NODES;
  const int kbase = ks * (N_NODES / NKS1);
  const int nt = (N_NODES / NKS1) / 32;

  __shared__ float sAdj[2][64 * 32];   // [buf][row][col], chunk-swizzled

  const bf16x4 qf = *(const bf16x4*)(Qn + (size_t)(q0 + lr) * C_DIM + lg * 4);
  const f32x4 zero = (f32x4){0.f, 0.f, 0.f, 0.f};
  f32x4 o = zero;
  float lsum = 0.f;
  const ushort* vrow = VT + (size_t)lr * N_NODES;

  // staging slots: sA=tid, sB=tid+256 (512 slots of 16B = 8KB)
  const int rowA = tid >> 3, cA = tid & 7;
  const int rowB = rowA + 32;
  const size_t aOffA = (size_t)rowA * N_NODES + ((size_t)(cA ^ (rowA & 7)) << 2);
  const size_t aOffB = (size_t)rowB * N_NODES + ((size_t)(cA ^ (rowB & 7)) << 2);
  const float* adjq = adj + (size_t)qblk * N_NODES;

#define STAGE1(BUF, K0)                                                        \
  {                                                                            \
    const float* asrc = adjq + (K0);                                           \
    __builtin_amdgcn_global_load_lds(asrc + aOffA,                             \
        (char*)&sAdj[BUF][0] + wid * 1024, 16, 0, 0);                          \
    __builtin_amdgcn_global_load_lds(asrc + aOffB,                             \
        (char*)&sAdj[BUF][0] + 4096 + wid * 1024, 16, 0, 0);                   \
  }

  STAGE1(0, kbase)

  const int rowL = wid * 16 + lr;
  const int adr0 = rowL * 32 + ((lg ^ (rowL & 7)) << 2);
  const int adr1 = rowL * 32 + (((4 + lg) ^ (rowL & 7)) << 2);

  for (int t = 0; t < nt; t++) {
    const int cur = t & 1;
    __syncthreads();
    if (t + 1 < nt) STAGE1(cur ^ 1, kbase + (t + 1) * 32)

    const int k0 = kbase + t * 32;
    bf16x4 kf0 = *(const bf16x4*)(Qn + (size_t)(k0 + lr) * C_DIM + lg * 4);
    bf16x4 kf1 = *(const bf16x4*)(Qn + (size_t)(k0 + 16 + lr) * C_DIM + lg * 4);
    f32x4 s0 = __builtin_amdgcn_mfma_f32_16x16x16bf16_1k(kf0, qf, zero, 0, 0, 0);
    f32x4 s1 = __builtin_amdgcn_mfma_f32_16x16x16bf16_1k(kf1, qf, zero, 0, 0, 0);
    f32x4 a0 = *(const f32x4*)&sAdj[cur][adr0];
    f32x4 a1 = *(const f32x4*)&sAdj[cur][adr1];
    bf16x4 pf0, pf1;
#pragma unroll
    for (int r = 0; r < 4; r++) {
      float e0 = exp2f(fmaf(s0[r], LOG2E, -SMAX));
      float e1 = exp2f(fmaf(s1[r], LOG2E, -SMAX));
      float p0 = e0 * (a0[r] + EPSF);
      float p1 = e1 * (a1[r] + EPSF);
      lsum += p0 + p1;
      pf0[r] = (short)f2bf(p0);
      pf1[r] = (short)f2bf(p1);
    }
    bf16x4 vf0 = *(const bf16x4*)(vrow + k0 + lg * 4);
    bf16x4 vf1 = *(const bf16x4*)(vrow + k0 + 16 + lg * 4);
    o = __builtin_amdgcn_mfma_f32_16x16x16bf16_1k(pf0, vf0, o, 0, 0, 0);
    o = __builtin_amdgcn_mfma_f32_16x16x16bf16_1k(pf1, vf1, o, 0, 0, 0);
  }
#undef STAGE1

  const int ps = b * NKS1 + ks;
  float psum = lsum;
  psum += __shfl_xor(psum, 16);
  psum += __shfl_xor(psum, 32);
  if (lg == 0) pl[(size_t)ps * N_NODES + q0 + lr] = psum;
#pragma unroll
  for (int r = 0; r < 4; r++)
    pacc[((size_t)ps * N_NODES + q0 + lg * 4 + r) * C_DIM + lr] = o[r];
}

// ---------------------------------------------------------------------------
// K5: merge the NKS1 K-split partials per (branch, row) — plain sums.
// ---------------------------------------------------------------------------
__global__ __launch_bounds__(256) void combine1_kernel(
    const float* __restrict__ pl, const float* __restrict__ pacc,
    float* __restrict__ o1)
{
  const int q = blockIdx.x * 256 + threadIdx.x;
  const int b = blockIdx.y;
  float L = 0.f;
  f32x4 out0 = (f32x4){0,0,0,0}, out1 = (f32x4){0,0,0,0},
        out2 = (f32x4){0,0,0,0}, out3 = (f32x4){0,0,0,0};
#pragma unroll
  for (int ks = 0; ks < NKS1; ks++) {
    const size_t pidx = (size_t)(b * NKS1 + ks) * N_NODES + q;
    L += pl[pidx];
    const f32x4* pa = (const f32x4*)(pacc + pidx * C_DIM);
    out0 += pa[0]; out1 += pa[1]; out2 += pa[2]; out3 += pa[3];
  }
  float invL = 1.0f / L;
  f32x4* dst = (f32x4*)(o1 + ((size_t)b * N_NODES + q) * C_DIM);
  dst[0] = out0 * invL; dst[1] = out1 * invL; dst[2] = out2 * invL; dst[3] = out3 * invL;
}

// ---------------------------------------------------------------------------
// K6: add biases, softmax(g1)-weighted branch mix, log_softmax over 16.
// ---------------------------------------------------------------------------
__global__ __launch_bounds__(256) void final_kernel(
    const float* __restrict__ o1,
    const float* __restrict__ bl1, const float* __restrict__ bh1,
    const float* __restrict__ bm1,
    const float* __restrict__ g1, float* __restrict__ out)
{
  const int q = blockIdx.x * 256 + threadIdx.x;
  float ga = g1[0], gb = g1[1], gc = g1[2];
  float gm = fmaxf(ga, fmaxf(gb, gc));
  float e0 = expf(ga - gm), e1 = expf(gb - gm), e2 = expf(gc - gm);
  float ei = 1.0f / (e0 + e1 + e2);
  float w0 = e0 * ei, w1 = e1 * ei, w2 = e2 * ei;
  const size_t NC = (size_t)N_NODES * C_DIM;

  float v[16];
#pragma unroll
  for (int i = 0; i < 4; i++) {
    f32x4 a = ((const f32x4*)(o1 + (size_t)q * C_DIM))[i];
    f32x4 bA = ((const f32x4*)(o1 + NC + (size_t)q * C_DIM))[i];
    f32x4 c = ((const f32x4*)(o1 + 2 * NC + (size_t)q * C_DIM))[i];
    f32x4 xl = ((const f32x4*)bl1)[i];
    f32x4 xh = ((const f32x4*)bh1)[i];
    f32x4 xm = ((const f32x4*)bm1)[i];
#pragma unroll
    for (int j = 0; j < 4; j++)
      v[i * 4 + j] = w0 * (a[j] + xl[j]) + w1 * (bA[j] + xh[j]) + w2 * (c[j] + xm[j]);
  }
  float mx = -1e30f;
#pragma unroll
  for (int j = 0; j < 16; j++) mx = fmaxf(mx, v[j]);
  float se = 0.f;
#pragma unroll
  for (int j = 0; j < 16; j++) se += expf(v[j] - mx);
  float lse = mx + logf(se);
  f32x4* dst = (f32x4*)(out + (size_t)q * C_DIM);
#pragma unroll
  for (int i = 0; i < 4; i++) {
    f32x4 r;
#pragma unroll
    for (int j = 0; j < 4; j++) r[j] = v[i * 4 + j] - lse;
    dst[i] = r;
  }
}

// ---------------------------------------------------------------------------
extern "C" void kernel_launch(void* const* d_in, const int* in_sizes, int n_in,
                              void* d_out, int out_size, void* d_ws, size_t ws_size,
                              hipStream_t stream) {
  (void)in_sizes; (void)n_in; (void)out_size; (void)ws_size;
  const float* x     = (const float*)d_in[0];
  const float* adj_l = (const float*)d_in[1];
  const float* adj_h = (const float*)d_in[2];
  const float* adj_m = (const float*)d_in[3];
  const float* w_l0  = (const float*)d_in[4];
  const float* b_l0  = (const float*)d_in[5];
  const float* w_h0  = (const float*)d_in[6];
  const float* b_h0  = (const float*)d_in[7];
  const float* w_m0  = (const float*)d_in[8];
  const float* b_m0  = (const float*)d_in[9];
  const float* w_l1  = (const float*)d_in[10];
  const float* b_l1  = (const float*)d_in[11];
  const float* w_h1  = (const float*)d_in[12];
  const float* b_h1  = (const float*)d_in[13];
  const float* w_m1  = (const float*)d_in[14];
  const float* b_m1  = (const float*)d_in[15];
  const float* g0    = (const float*)d_in[16];
  const float* g1    = (const float*)d_in[17];
  float* out = (float*)d_out;

  char* ws = (char*)d_ws;
  // persistent:
  ushort* hn  = (ushort*)(ws);                  // [0, 3MB)
  ushort* hvT = (ushort*)(ws + (3u << 20));     // [3MB, 6MB)
  ushort* hn1b= (ushort*)(ws + (6u << 20));                 // 384KB
  ushort* hbT = (ushort*)(ws + (6u << 20) + (384u << 10));  // 384KB
  // phase A (layer-0 partials, dead after mix1):
  float*  pl0 = (float*)(ws + (12u << 20));                    // 192KB
  ushort* pO  = (ushort*)(ws + (12u << 20) + (512u << 10));    // 12MB (bf16)
  // phase B (layer-1 scratch), reuses phase-A region after mix1:
  float*  pl  = (float*)(ws + (12u << 20));                    // 384KB
  float*  pacc= (float*)(ws + (13u << 20));                    // 6MB
  float*  o1  = (float*)(ws + (20u << 20));                    // 768KB

  proj0_kernel<<<dim3(512), dim3(256), 0, stream>>>(x, w_l0, w_h0, w_m0, hn, hvT);
  flash0_kernel<<<dim3(64, NKS0, 3), dim3(256), 0, stream>>>(hn, hvT, adj_l, adj_h, adj_m,
                                                             pl0, pO);
  mix1_kernel<<<dim3(4096), dim3(128), 0, stream>>>(pl0, pO, b_l0, b_h0, b_m0,
                                                    w_l1, w_h1, w_m1, g0, hn1b, hbT);
  flash1_kernel<<<dim3(64, NKS1, 3), dim3(256), 0, stream>>>(hn1b, hbT, adj_l, adj_h, adj_m,
                                                             pl, pacc);
  combine1_kernel<<<dim3(16, 3), dim3(256), 0, stream>>>(pl, pacc, o1);
  final_kernel<<<dim3(16), dim3(256), 0, stream>>>(o1, b_l1, b_h1, b_m1, g1, out);
}

// Round 19
// 162.135 us; speedup vs baseline: 1.1366x; 1.1366x over previous
//
#include <hip/hip_runtime.h>

#define N_NODES 4096
#define F_IN 512
#define H_DIM 128
#define C_DIM 16
#define EPSF 1e-8f
#define LOG2E 1.4426950408889634f
#define SMAX 2.0f   // static softmax max: logits = cos/tau*log2e + log2(adj+eps) < 2 always
#define NKS0 8      // layer-0 K-splits
#define KLEN0 (N_NODES / NKS0)
#define NT0 (KLEN0 / 32)
#define NKS1 8      // layer-1 K-splits

typedef __attribute__((ext_vector_type(8))) short bf16x8;
typedef __attribute__((ext_vector_type(4))) short bf16x4;
typedef __attribute__((ext_vector_type(4))) float f32x4;

__device__ __forceinline__ ushort f2bf(float f){
  union { float f; unsigned u; } v; v.f = f;
  unsigned u = v.u;
  return (ushort)((u + 0x7fffu + ((u >> 16) & 1u)) >> 16);
}
__device__ __forceinline__ float bf2f(ushort h){
  union { unsigned u; float f; } v; v.u = ((unsigned)h) << 16;
  return v.f;
}

// ---------------------------------------------------------------------------
// K1: h = x @ W0 for 3 branches, k-split x2 within block (256 thr, 4 waves);
//     row norms; write hn (bf16, row-major) and hvT (bf16 [3][128][4096]).
// ---------------------------------------------------------------------------
__global__ __launch_bounds__(256) void proj0_kernel(
    const float* __restrict__ x,
    const float* __restrict__ Wl, const float* __restrict__ Wh,
    const float* __restrict__ Wm,
    ushort* __restrict__ hn, ushort* __restrict__ hvT)
{
  const int t = threadIdx.x;
  const int d = t & 127;
  const int half = t >> 7;
  const int r0 = blockIdx.x * 8;
  __shared__ float xs[8][F_IN];
  for (int i = t; i < 8 * F_IN; i += 256)
    xs[i >> 9][i & 511] = x[(size_t)(r0 + (i >> 9)) * F_IN + (i & 511)];
  __syncthreads();

  float acc0[8], acc1[8], acc2[8];
#pragma unroll
  for (int r = 0; r < 8; r++) { acc0[r] = 0.f; acc1[r] = 0.f; acc2[r] = 0.f; }

  const int k0 = half * (F_IN / 2);
  for (int k = k0; k < k0 + F_IN / 2; k++) {
    float wl = Wl[k * H_DIM + d];
    float wh = Wh[k * H_DIM + d];
    float wm = Wm[k * H_DIM + d];
#pragma unroll
    for (int r = 0; r < 8; r++) {
      float xv = xs[r][k];
      acc0[r] = fmaf(xv, wl, acc0[r]);
      acc1[r] = fmaf(xv, wh, acc1[r]);
      acc2[r] = fmaf(xv, wm, acc2[r]);
    }
  }

  // cross-half combine
  __shared__ float part[3][8][128];
  if (half == 1) {
#pragma unroll
    for (int r = 0; r < 8; r++) {
      part[0][r][d] = acc0[r]; part[1][r][d] = acc1[r]; part[2][r][d] = acc2[r];
    }
  }
  __syncthreads();
  if (half == 0) {
#pragma unroll
    for (int r = 0; r < 8; r++) {
      acc0[r] += part[0][r][d]; acc1[r] += part[1][r][d]; acc2[r] += part[2][r][d];
    }
  }

  __shared__ float red[24][2];
  const int wv = t >> 6;        // 0..1 for half==0
  const int lane = t & 63;

#define REDUCE_BRANCH(ACC, B)                                        \
  _Pragma("unroll")                                                  \
  for (int r = 0; r < 8; r++) {                                      \
    float v = ACC[r] * ACC[r];                                       \
    v += __shfl_down(v, 32); v += __shfl_down(v, 16);                \
    v += __shfl_down(v, 8);  v += __shfl_down(v, 4);                 \
    v += __shfl_down(v, 2);  v += __shfl_down(v, 1);                 \
    if (lane == 0) red[(B) * 8 + r][wv] = v;                         \
  }
  if (half == 0) {
    REDUCE_BRANCH(acc0, 0)
    REDUCE_BRANCH(acc1, 1)
    REDUCE_BRANCH(acc2, 2)
  }
  __syncthreads();

#define WRITE_BRANCH(ACC, B)                                                   \
  _Pragma("unroll")                                                            \
  for (int r = 0; r < 8; r++) {                                                \
    float nrm = sqrtf(red[(B) * 8 + r][0] + red[(B) * 8 + r][1]);              \
    float rn = 1.0f / fmaxf(nrm, EPSF);                                        \
    float h = ACC[r];                                                          \
    hn[((size_t)(B) * N_NODES + r0 + r) * H_DIM + d] = f2bf(h * rn);           \
    hvT[((size_t)(B) * H_DIM + d) * N_NODES + r0 + r] = f2bf(h);               \
  }
  if (half == 0) {
    WRITE_BRANCH(acc0, 0)
    WRITE_BRANCH(acc1, 1)
    WRITE_BRANCH(acc2, 2)
  }
#undef REDUCE_BRANCH
#undef WRITE_BRANCH
}

// ---------------------------------------------------------------------------
// K2: flash attention layer 0 — R13-verified dataflow (swapped QK^T,
//     in-register P) with adj staged via global_load_lds (best-measured
//     config, R17: flash0 ~94us). 6 vmem ops/wave/tile, counted vmcnt(6),
//     raw barrier pairs. 4 waves/block, 64 q-rows.
// ---------------------------------------------------------------------------
__global__ __launch_bounds__(256) void flash0_kernel(
    const ushort* __restrict__ hn, const ushort* __restrict__ hvT,
    const float* __restrict__ adj_l, const float* __restrict__ adj_h,
    const float* __restrict__ adj_m,
    float* __restrict__ pl0, ushort* __restrict__ pO)
{
  const int tid = threadIdx.x;
  const int w = tid >> 6;
  const int lane = tid & 63;
  const int lr = lane & 15;
  const int lg = lane >> 4;
  const int ks = blockIdx.y;
  const int b = blockIdx.z;
  const int qblk = blockIdx.x * 64;
  const int q0 = qblk + w * 16;
  const float* adj = (b == 0) ? adj_l : (b == 1) ? adj_h : adj_m;
  const ushort* Qg = hn + (size_t)b * N_NODES * H_DIM;
  const ushort* VTg = hvT + (size_t)b * H_DIM * N_NODES;
  const int kbase = ks * KLEN0;

  __shared__ ushort sK[2][32 * 128];   // [buf][k-row][d], chunk-swizzled (8KB)
  __shared__ ushort sV[2][128 * 32];   // [buf][d-row][k], chunk-swizzled (8KB)
  __shared__ float  sAdj[2][64 * 32];  // [buf][local q-row][k], chunk-swizzled (8KB)

  // Q B-fragments (one-time global read)
  bf16x8 qf[4];
  {
    const ushort* qp = Qg + (size_t)(q0 + lr) * H_DIM + lg * 8;
#pragma unroll
    for (int u = 0; u < 4; u++) qf[u] = *(const bf16x8*)(qp + 32 * u);
  }

  f32x4 o[8];
#pragma unroll
  for (int dt = 0; dt < 8; dt++) o[dt] = (f32x4){0.f, 0.f, 0.f, 0.f};
  float lsum = 0.f;

  // --- staging slot decomposition (R8-verified for K/V; flash1-verified for adj) ---
  const int sA = w * 128 + lane;
  const int sB = sA + 64;
  const int kkA = sA >> 4, kcA = sA & 15;
  const int kkB = sB >> 4, kcB = sB & 15;
  const size_t kOffA = (size_t)kkA * H_DIM + ((size_t)(kcA ^ (kkA & 7)) << 3);
  const size_t kOffB = (size_t)kkB * H_DIM + ((size_t)(kcB ^ (kkB & 7)) << 3);
  const int dA = sA >> 2, vcA = sA & 3;
  const int dB = sB >> 2, vcB = sB & 3;
  const size_t vOffA = (size_t)dA * N_NODES + ((size_t)(vcA ^ ((dA >> 1) & 3)) << 3);
  const size_t vOffB = (size_t)dB * N_NODES + ((size_t)(vcB ^ ((dB >> 1) & 3)) << 3);
  // adj units: [64 rows][8 chunks of 16B]; thread stages units tid, tid+256
  const int arw1 = tid >> 3, ac1 = tid & 7;
  const int arw2 = arw1 + 32;
  const size_t aOff1 = (size_t)arw1 * N_NODES + ((size_t)(ac1 ^ (arw1 & 7)) << 2);
  const size_t aOff2 = (size_t)arw2 * N_NODES + ((size_t)(ac1 ^ (arw2 & 7)) << 2);
  const float* adjq = adj + (size_t)qblk * N_NODES;

#define STAGE(BUF, K0)                                                         \
  {                                                                            \
    const ushort* ksrc = Qg + (size_t)(K0) * H_DIM;                            \
    const ushort* vsrc = VTg + (K0);                                           \
    const float*  asrc = adjq + (K0);                                          \
    __builtin_amdgcn_global_load_lds(ksrc + kOffA,                             \
        (char*)&sK[BUF][0] + w * 2048, 16, 0, 0);                              \
    __builtin_amdgcn_global_load_lds(ksrc + kOffB,                             \
        (char*)&sK[BUF][0] + w * 2048 + 1024, 16, 0, 0);                       \
    __builtin_amdgcn_global_load_lds(vsrc + vOffA,                             \
        (char*)&sV[BUF][0] + w * 2048, 16, 0, 0);                              \
    __builtin_amdgcn_global_load_lds(vsrc + vOffB,                             \
        (char*)&sV[BUF][0] + w * 2048 + 1024, 16, 0, 0);                       \
    __builtin_amdgcn_global_load_lds(asrc + aOff1,                             \
        (char*)&sAdj[BUF][0] + w * 1024, 16, 0, 0);                            \
    __builtin_amdgcn_global_load_lds(asrc + aOff2,                             \
        (char*)&sAdj[BUF][0] + 4096 + w * 1024, 16, 0, 0);                     \
  }

  STAGE(0, kbase)

  // adj read offsets (swizzled): lane (lr) reads local row rL = w*16+lr,
  // chunks lg (a0) and 4+lg (a1)
  const int rL = w * 16 + lr;
  const int adr0 = rL * 32 + ((lg ^ (rL & 7)) << 2);
  const int adr1 = rL * 32 + (((4 + lg) ^ (rL & 7)) << 2);

  for (int t = 0; t < NT0; t++) {
    const int cur = t & 1;
    // barrier A: all waves done computing tile t-1 (frees buf cur^1)
    __builtin_amdgcn_s_barrier();
    __builtin_amdgcn_sched_barrier(0);
    if (t + 1 < NT0) STAGE(cur ^ 1, kbase + (t + 1) * 32)
    // counted wait: STAGE(t) landed; STAGE(t+1)'s 6 ops stay in flight
    if (t + 1 < NT0) { asm volatile("s_waitcnt vmcnt(6)" ::: "memory"); }
    else             { asm volatile("s_waitcnt vmcnt(0)" ::: "memory"); }
    __builtin_amdgcn_sched_barrier(0);
    // barrier B: ALL waves' STAGE(t) slices landed
    __builtin_amdgcn_s_barrier();
    __builtin_amdgcn_sched_barrier(0);

    __builtin_amdgcn_s_setprio(1);
    // --- swapped QK^T from LDS: s = mfma(K, Q) -> lane holds S^T ---
    f32x4 s0 = (f32x4){0.f, 0.f, 0.f, 0.f};
    f32x4 s1 = (f32x4){0.f, 0.f, 0.f, 0.f};
    const char* sKc = (const char*)&sK[cur][0];
#pragma unroll
    for (int u = 0; u < 4; u++) {
      const int c0 = lg + 4 * u;
      bf16x8 kf0 = *(const bf16x8*)(sKc + lr * 256 + ((c0 ^ (lr & 7)) << 4));
      bf16x8 kf1 = *(const bf16x8*)(sKc + (lr + 16) * 256 + ((c0 ^ (lr & 7)) << 4));
      s0 = __builtin_amdgcn_mfma_f32_16x16x32_bf16(kf0, qf[u], s0, 0, 0, 0);
      s1 = __builtin_amdgcn_mfma_f32_16x16x32_bf16(kf1, qf[u], s1, 0, 0, 0);
    }
    // adj from LDS (2-way banks)
    f32x4 a0 = *(const f32x4*)&sAdj[cur][adr0];
    f32x4 a1 = *(const f32x4*)&sAdj[cur][adr1];
    // --- softmax numerator in registers: P stays as PV A-fragments ---
    bf16x4 pf0, pf1;
#pragma unroll
    for (int r = 0; r < 4; r++) {
      float p0 = exp2f(fmaf(s0[r], LOG2E, -SMAX)) * (a0[r] + EPSF);
      float p1 = exp2f(fmaf(s1[r], LOG2E, -SMAX)) * (a1[r] + EPSF);
      lsum += p0 + p1;
      pf0[r] = (short)f2bf(p0);
      pf1[r] = (short)f2bf(p1);
    }
    // --- PV from LDS: o[dt] accumulates P[16q][32k] @ V[32k][16d] ---
    const char* sVc = (const char*)&sV[cur][0];
#pragma unroll
    for (int dt = 0; dt < 8; dt++) {
      const int dd = dt * 16 + lr;
      const int sw = (dd >> 1) & 3;
      bf16x4 vf0 = *(const bf16x4*)(sVc + dd * 64 +
                     ((((lg >> 1) + 0) ^ sw) << 4) + (lg & 1) * 8);
      bf16x4 vf1 = *(const bf16x4*)(sVc + dd * 64 +
                     ((((lg >> 1) + 2) ^ sw) << 4) + (lg & 1) * 8);
      o[dt] = __builtin_amdgcn_mfma_f32_16x16x16bf16_1k(pf0, vf0, o[dt], 0, 0, 0);
      o[dt] = __builtin_amdgcn_mfma_f32_16x16x16bf16_1k(pf1, vf1, o[dt], 0, 0, 0);
    }
    __builtin_amdgcn_s_setprio(0);
  }
#undef STAGE

  const int ps = b * NKS0 + ks;
  // denominator: lane (lr,lg) holds partial for q0+lr over its k-slice
  float psum = lsum;
  psum += __shfl_xor(psum, 16);
  psum += __shfl_xor(psum, 32);
  if (lg == 0) pl0[(size_t)ps * N_NODES + q0 + lr] = psum;
  // numerators: o[dt] C/D: row = q0+lg*4+r, col = dt*16+lr (R4-verified)
#pragma unroll
  for (int dt = 0; dt < 8; dt++) {
#pragma unroll
    for (int r = 0; r < 4; r++) {
      pO[((size_t)ps * N_NODES + q0 + lg * 4 + r) * H_DIM + dt * 16 + lr] =
          f2bf(o[dt][r]);
    }
  }
}

// ---------------------------------------------------------------------------
// K3: fused combine0+mix1: merge K-split partials, branch mix + relu, @W1,
//     row norms -> hn1b (bf16 [3][4096][16]); hbT (bf16 [3][16][4096]).
// ---------------------------------------------------------------------------
__global__ __launch_bounds__(128) void mix1_kernel(
    const float* __restrict__ pl0, const ushort* __restrict__ pO,
    const float* __restrict__ bl0, const float* __restrict__ bh0,
    const float* __restrict__ bm0,
    const float* __restrict__ Wl1, const float* __restrict__ Wh1,
    const float* __restrict__ Wm1,
    const float* __restrict__ g0,
    ushort* __restrict__ hn1b, ushort* __restrict__ hbT)
{
  const int q = blockIdx.x;
  const int t = threadIdx.x;
  float ga = g0[0], gb = g0[1], gc = g0[2];
  float gm = fmaxf(ga, fmaxf(gb, gc));
  float e0 = expf(ga - gm), e1 = expf(gb - gm), e2 = expf(gc - gm);
  float ei = 1.0f / (e0 + e1 + e2);

  __shared__ float Ls[3];
  if (t < 3) {
    float L = 0.f;
#pragma unroll
    for (int ks = 0; ks < NKS0; ks++) L += pl0[(size_t)(t * NKS0 + ks) * N_NODES + q];
    Ls[t] = L;
  }
  float O0 = 0.f, O1 = 0.f, O2 = 0.f;
#pragma unroll
  for (int ks = 0; ks < NKS0; ks++) {
    O0 += bf2f(pO[((size_t)(0 * NKS0 + ks) * N_NODES + q) * H_DIM + t]);
    O1 += bf2f(pO[((size_t)(1 * NKS0 + ks) * N_NODES + q) * H_DIM + t]);
    O2 += bf2f(pO[((size_t)(2 * NKS0 + ks) * N_NODES + q) * H_DIM + t]);
  }
  __syncthreads();

  __shared__ float hc[H_DIM];
  hc[t] = e0 * ei * fmaxf(O0 / Ls[0] + bl0[t], 0.f)
        + e1 * ei * fmaxf(O1 / Ls[1] + bh0[t], 0.f)
        + e2 * ei * fmaxf(O2 / Ls[2] + bm0[t], 0.f);
  __syncthreads();

  __shared__ float shb[48];
  if (t < 48) {
    const int b = t >> 4, j = t & 15;
    const float* W = (b == 0) ? Wl1 : (b == 1) ? Wh1 : Wm1;
    float s = 0.f;
    for (int k = 0; k < H_DIM; k++) s = fmaf(hc[k], W[k * C_DIM + j], s);
    shb[t] = s;
  }
  __syncthreads();
  __shared__ float rns[3];
  if (t < 3) {
    float s = 0.f;
#pragma unroll
    for (int j = 0; j < C_DIM; j++) { float u = shb[t * C_DIM + j]; s = fmaf(u, u, s); }
    rns[t] = 1.0f / fmaxf(sqrtf(s), EPSF);
  }
  __syncthreads();
  if (t < 48) {
    const int b = t >> 4, j = t & 15;
    hbT[((size_t)b * C_DIM + j) * N_NODES + q] = f2bf(shb[t]);
    hn1b[((size_t)b * N_NODES + q) * C_DIM + j] = f2bf(shb[t] * rns[b]);
  }
}

// ---------------------------------------------------------------------------
// K4: flash attention layer 1, D=16, MFMA 16x16x16, swapped QK^T, K-split 8.
//     adj staged in LDS [64 q-rows][32 k] double-buffered via global_load_lds
//     (XOR-chunk swizzle both sides); Q/K/V direct (L2-resident).
// ---------------------------------------------------------------------------
__global__ __launch_bounds__(256) void flash1_kernel(
    const ushort* __restrict__ hn1b, const ushort* __restrict__ hbT,
    const float* __restrict__ adj_l, const float* __restrict__ adj_h,
    const float* __restrict__ adj_m,
    float* __restrict__ pl, float* __restrict__ pacc)
{
  const int tid = threadIdx.x;
  const int wid = tid >> 6;
  const int lane = tid & 63;
  const int lr = lane & 15;
  const int lg = lane >> 4;
  const int qblk = blockIdx.x * 64;
  const int q0 = qblk + wid * 16;
  const int ks = blockIdx.y;
  const int b = blockIdx.z;
  const float* adj = (b == 0) ? adj_l : (b == 1) ? adj_h : adj_m;
  const ushort* Qn = hn1b + (size_t)b * N_NODES * C_DIM;
  const ushort* VT = hbT + (size_t)b * C_DIM * N_NODES;
  const int kbase = ks * (N_NODES / NKS1);
  const int nt = (N_NODES / NKS1) / 32;

  __shared__ float sAdj[2][64 * 32];   // [buf][row][col], chunk-swizzled

  const bf16x4 qf = *(const bf16x4*)(Qn + (size_t)(q0 + lr) * C_DIM + lg * 4);
  const f32x4 zero = (f32x4){0.f, 0.f, 0.f, 0.f};
  f32x4 o = zero;
  float lsum = 0.f;
  const ushort* vrow = VT + (size_t)lr * N_NODES;

  // staging slots: sA=tid, sB=tid+256 (512 slots of 16B = 8KB)
  const int rowA = tid >> 3, cA = tid & 7;
  const int rowB = rowA + 32;
  const size_t aOffA = (size_t)rowA * N_NODES + ((size_t)(cA ^ (rowA & 7)) << 2);
  const size_t aOffB = (size_t)rowB * N_NODES + ((size_t)(cA ^ (rowB & 7)) << 2);
  const float* adjq = adj + (size_t)qblk * N_NODES;

#define STAGE1(BUF, K0)                                                        \
  {                                                                            \
    const float* asrc = adjq + (K0);                                           \
    __builtin_amdgcn_global_load_lds(asrc + aOffA,                             \
        (char*)&sAdj[BUF][0] + wid * 1024, 16, 0, 0);                          \
    __builtin_amdgcn_global_load_lds(asrc + aOffB,                             \
        (char*)&sAdj[BUF][0] + 4096 + wid * 1024, 16, 0, 0);                   \
  }

  STAGE1(0, kbase)

  const int rowL = wid * 16 + lr;
  const int adr0 = rowL * 32 + ((lg ^ (rowL & 7)) << 2);
  const int adr1 = rowL * 32 + (((4 + lg) ^ (rowL & 7)) << 2);

  for (int t = 0; t < nt; t++) {
    const int cur = t & 1;
    __syncthreads();
    if (t + 1 < nt) STAGE1(cur ^ 1, kbase + (t + 1) * 32)

    const int k0 = kbase + t * 32;
    bf16x4 kf0 = *(const bf16x4*)(Qn + (size_t)(k0 + lr) * C_DIM + lg * 4);
    bf16x4 kf1 = *(const bf16x4*)(Qn + (size_t)(k0 + 16 + lr) * C_DIM + lg * 4);
    f32x4 s0 = __builtin_amdgcn_mfma_f32_16x16x16bf16_1k(kf0, qf, zero, 0, 0, 0);
    f32x4 s1 = __builtin_amdgcn_mfma_f32_16x16x16bf16_1k(kf1, qf, zero, 0, 0, 0);
    f32x4 a0 = *(const f32x4*)&sAdj[cur][adr0];
    f32x4 a1 = *(const f32x4*)&sAdj[cur][adr1];
    bf16x4 pf0, pf1;
#pragma unroll
    for (int r = 0; r < 4; r++) {
      float e0 = exp2f(fmaf(s0[r], LOG2E, -SMAX));
      float e1 = exp2f(fmaf(s1[r], LOG2E, -SMAX));
      float p0 = e0 * (a0[r] + EPSF);
      float p1 = e1 * (a1[r] + EPSF);
      lsum += p0 + p1;
      pf0[r] = (short)f2bf(p0);
      pf1[r] = (short)f2bf(p1);
    }
    bf16x4 vf0 = *(const bf16x4*)(vrow + k0 + lg * 4);
    bf16x4 vf1 = *(const bf16x4*)(vrow + k0 + 16 + lg * 4);
    o = __builtin_amdgcn_mfma_f32_16x16x16bf16_1k(pf0, vf0, o, 0, 0, 0);
    o = __builtin_amdgcn_mfma_f32_16x16x16bf16_1k(pf1, vf1, o, 0, 0, 0);
  }
#undef STAGE1

  const int ps = b * NKS1 + ks;
  float psum = lsum;
  psum += __shfl_xor(psum, 16);
  psum += __shfl_xor(psum, 32);
  if (lg == 0) pl[(size_t)ps * N_NODES + q0 + lr] = psum;
#pragma unroll
  for (int r = 0; r < 4; r++)
    pacc[((size_t)ps * N_NODES + q0 + lg * 4 + r) * C_DIM + lr] = o[r];
}

// ---------------------------------------------------------------------------
// K5: merge the NKS1 K-split partials per (branch, row) — plain sums.
// ---------------------------------------------------------------------------
__global__ __launch_bounds__(256) void combine1_kernel(
    const float* __restrict__ pl, const float* __restrict__ pacc,
    float* __restrict__ o1)
{
  const int q = blockIdx.x * 256 + threadIdx.x;
  const int b = blockIdx.y;
  float L = 0.f;
  f32x4 out0 = (f32x4){0,0,0,0}, out1 = (f32x4){0,0,0,0},
        out2 = (f32x4){0,0,0,0}, out3 = (f32x4){0,0,0,0};
#pragma unroll
  for (int ks = 0; ks < NKS1; ks++) {
    const size_t pidx = (size_t)(b * NKS1 + ks) * N_NODES + q;
    L += pl[pidx];
    const f32x4* pa = (const f32x4*)(pacc + pidx * C_DIM);
    out0 += pa[0]; out1 += pa[1]; out2 += pa[2]; out3 += pa[3];
  }
  float invL = 1.0f / L;
  f32x4* dst = (f32x4*)(o1 + ((size_t)b * N_NODES + q) * C_DIM);
  dst[0] = out0 * invL; dst[1] = out1 * invL; dst[2] = out2 * invL; dst[3] = out3 * invL;
}

// ---------------------------------------------------------------------------
// K6: add biases, softmax(g1)-weighted branch mix, log_softmax over 16.
// ---------------------------------------------------------------------------
__global__ __launch_bounds__(256) void final_kernel(
    const float* __restrict__ o1,
    const float* __restrict__ bl1, const float* __restrict__ bh1,
    const float* __restrict__ bm1,
    const float* __restrict__ g1, float* __restrict__ out)
{
  const int q = blockIdx.x * 256 + threadIdx.x;
  float ga = g1[0], gb = g1[1], gc = g1[2];
  float gm = fmaxf(ga, fmaxf(gb, gc));
  float e0 = expf(ga - gm), e1 = expf(gb - gm), e2 = expf(gc - gm);
  float ei = 1.0f / (e0 + e1 + e2);
  float w0 = e0 * ei, w1 = e1 * ei, w2 = e2 * ei;
  const size_t NC = (size_t)N_NODES * C_DIM;

  float v[16];
#pragma unroll
  for (int i = 0; i < 4; i++) {
    f32x4 a = ((const f32x4*)(o1 + (size_t)q * C_DIM))[i];
    f32x4 bA = ((const f32x4*)(o1 + NC + (size_t)q * C_DIM))[i];
    f32x4 c = ((const f32x4*)(o1 + 2 * NC + (size_t)q * C_DIM))[i];
    f32x4 xl = ((const f32x4*)bl1)[i];
    f32x4 xh = ((const f32x4*)bh1)[i];
    f32x4 xm = ((const f32x4*)bm1)[i];
#pragma unroll
    for (int j = 0; j < 4; j++)
      v[i * 4 + j] = w0 * (a[j] + xl[j]) + w1 * (bA[j] + xh[j]) + w2 * (c[j] + xm[j]);
  }
  float mx = -1e30f;
#pragma unroll
  for (int j = 0; j < 16; j++) mx = fmaxf(mx, v[j]);
  float se = 0.f;
#pragma unroll
  for (int j = 0; j < 16; j++) se += expf(v[j] - mx);
  float lse = mx + logf(se);
  f32x4* dst = (f32x4*)(out + (size_t)q * C_DIM);
#pragma unroll
  for (int i = 0; i < 4; i++) {
    f32x4 r;
#pragma unroll
    for (int j = 0; j < 4; j++) r[j] = v[i * 4 + j] - lse;
    dst[i] = r;
  }
}

// ---------------------------------------------------------------------------
extern "C" void kernel_launch(void* const* d_in, const int* in_sizes, int n_in,
                              void* d_out, int out_size, void* d_ws, size_t ws_size,
                              hipStream_t stream) {
  (void)in_sizes; (void)n_in; (void)out_size; (void)ws_size;
  const float* x     = (const float*)d_in[0];
  const float* adj_l = (const float*)d_in[1];
  const float* adj_h = (const float*)d_in[2];
  const float* adj_m = (const float*)d_in[3];
  const float* w_l0  = (const float*)d_in[4];
  const float* b_l0  = (const float*)d_in[5];
  const float* w_h0  = (const float*)d_in[6];
  const float* b_h0  = (const float*)d_in[7];
  const float* w_m0  = (const float*)d_in[8];
  const float* b_m0  = (const float*)d_in[9];
  const float* w_l1  = (const float*)d_in[10];
  const float* b_l1  = (const float*)d_in[11];
  const float* w_h1  = (const float*)d_in[12];
  const float* b_h1  = (const float*)d_in[13];
  const float* w_m1  = (const float*)d_in[14];
  const float* b_m1  = (const float*)d_in[15];
  const float* g0    = (const float*)d_in[16];
  const float* g1    = (const float*)d_in[17];
  float* out = (float*)d_out;

  char* ws = (char*)d_ws;
  // persistent:
  ushort* hn  = (ushort*)(ws);                  // [0, 3MB)
  ushort* hvT = (ushort*)(ws + (3u << 20));     // [3MB, 6MB)
  ushort* hn1b= (ushort*)(ws + (6u << 20));                 // 384KB
  ushort* hbT = (ushort*)(ws + (6u << 20) + (384u << 10));  // 384KB
  // phase A (layer-0 partials, dead after mix1):
  float*  pl0 = (float*)(ws + (12u << 20));                    // 384KB
  ushort* pO  = (ushort*)(ws + (12u << 20) + (512u << 10));    // 24MB (bf16)
  // phase B (layer-1 scratch), reuses phase-A region after mix1:
  float*  pl  = (float*)(ws + (12u << 20));                    // 384KB
  float*  pacc= (float*)(ws + (13u << 20));                    // 6MB
  float*  o1  = (float*)(ws + (20u << 20));                    // 768KB

  proj0_kernel<<<dim3(512), dim3(256), 0, stream>>>(x, w_l0, w_h0, w_m0, hn, hvT);
  flash0_kernel<<<dim3(64, NKS0, 3), dim3(256), 0, stream>>>(hn, hvT, adj_l, adj_h, adj_m,
                                                             pl0, pO);
  mix1_kernel<<<dim3(4096), dim3(128), 0, stream>>>(pl0, pO, b_l0, b_h0, b_m0,
                                                    w_l1, w_h1, w_m1, g0, hn1b, hbT);
  flash1_kernel<<<dim3(64, NKS1, 3), dim3(256), 0, stream>>>(hn1b, hbT, adj_l, adj_h, adj_m,
                                                             pl, pacc);
  combine1_kernel<<<dim3(16, 3), dim3(256), 0, stream>>>(pl, pacc, o1);
  final_kernel<<<dim3(16), dim3(256), 0, stream>>>(o1, b_l1, b_h1, b_m1, g1, out);
}